// Round 1
// baseline (554.812 us; speedup 1.0000x reference)
//
#include <hip/hip_runtime.h>
#include <math.h>

#define NN 25000
#define NE 400000
#define HID 64
#define F_IN 256
#define N_CLASS 32
#define MAXL 4          // x_all stores up to 4 layer slices
#define KV_STRIDE 3     // K/V layer stride (max 3 layers)

// ---------- degree / norm ----------
__global__ void deg_kernel(const int* __restrict__ col, int* __restrict__ deg, int E) {
    int e = blockIdx.x * blockDim.x + threadIdx.x;
    if (e < E) atomicAdd(&deg[col[e]], 1);
}

__global__ void dis_kernel(const int* __restrict__ deg, float* __restrict__ dis, int n) {
    int i = blockIdx.x * blockDim.x + threadIdx.x;
    if (i < n) dis[i] = rsqrtf((float)(deg[i] + 1));  // +1 self loop; always > 0
}

// ---------- lin1: h = relu(x @ W1 + b1), write into x_all layer 0 ----------
__global__ void lin1_kernel(const float* __restrict__ x, const float* __restrict__ w,
                            const float* __restrict__ b, float* __restrict__ x_all, int n) {
    __shared__ float xs[4][F_IN];
    int n0 = blockIdx.x * 4;
    int t = threadIdx.x;
    #pragma unroll
    for (int i = 0; i < 4; ++i) {
        int node = n0 + i;
        xs[i][t] = (node < n) ? x[(size_t)node * F_IN + t] : 0.f;
    }
    __syncthreads();
    int i = t >> 6, o = t & 63;
    int node = n0 + i;
    if (node >= n) return;
    float acc = b[o];
    for (int k = 0; k < F_IN; ++k) acc = fmaf(xs[i][k], w[k * HID + o], acc);
    x_all[(size_t)node * (MAXL * HID) + o] = fmaxf(acc, 0.f);
}

// ---------- per-node q/k/v grouped-linear transform for one conv layer ----------
// grouped_linear: out[d] = b[d] + sum_i x[g*8+i] * w[g*64 + i*8 + o], g=d>>3, o=d&7
__global__ void transform_kernel(const float* __restrict__ x_all,
                                 const float* __restrict__ wq, const float* __restrict__ bq,
                                 const float* __restrict__ wk, const float* __restrict__ bk,
                                 const float* __restrict__ wv, const float* __restrict__ bv,
                                 float* __restrict__ Q, float* __restrict__ K,
                                 float* __restrict__ V, int n, int L) {
    int t = blockIdx.x * blockDim.x + threadIdx.x;
    int node = t >> 6, d = t & 63;
    if (node >= n) return;
    int g = d >> 3, o = d & 7;
    const float* xrow = x_all + (size_t)node * (MAXL * HID);

    {   // Q from last layer (L-1)
        const float* xg = xrow + (L - 1) * HID + g * 8;
        const float* wg = wq + g * 64 + o;
        float acc = bq[d];
        #pragma unroll
        for (int i = 0; i < 8; ++i) acc = fmaf(xg[i], wg[i * 8], acc);
        Q[(size_t)node * HID + d] = acc;
    }
    for (int ll = 0; ll < L; ++ll) {
        const float* xg = xrow + ll * HID + g * 8;
        const float* wgk = wk + g * 64 + o;
        const float* wgv = wv + g * 64 + o;
        float ak = bk[d], av = bv[d];
        #pragma unroll
        for (int i = 0; i < 8; ++i) {
            ak = fmaf(xg[i], wgk[i * 8], ak);
            av = fmaf(xg[i], wgv[i * 8], av);
        }
        K[((size_t)node * KV_STRIDE + ll) * HID + d] = ak;
        V[((size_t)node * KV_STRIDE + ll) * HID + d] = av;
    }
}

// ---------- edge pass: one wave64 per edge; lane = output dim; head = lane>>3 ----------
template <int L>
__global__ void edge_kernel(const int* __restrict__ row, const int* __restrict__ colA,
                            const float* __restrict__ dis,
                            const float* __restrict__ Q, const float* __restrict__ K,
                            const float* __restrict__ V, float* __restrict__ acc,
                            int E, int Ee) {
    int wave = (int)((blockIdx.x * (size_t)blockDim.x + threadIdx.x) >> 6);
    int lane = threadIdx.x & 63;
    if (wave >= Ee) return;
    int r, c;
    if (wave < E) { r = row[wave]; c = colA[wave]; }
    else          { r = c = wave - E; }               // self loop
    float nrm = dis[r] * dis[c];
    float q = Q[(size_t)c * HID + lane];

    float s[L];
    #pragma unroll
    for (int ll = 0; ll < L; ++ll) {
        float kv = K[((size_t)r * KV_STRIDE + ll) * HID + lane];
        float p = q * kv;
        p += __shfl_xor(p, 1);    // reduce within the 8-lane head group
        p += __shfl_xor(p, 2);
        p += __shfl_xor(p, 4);
        s[ll] = p * 0.35355339059327373f;   // 1/sqrt(8)
    }
    float m = s[0];
    #pragma unroll
    for (int ll = 1; ll < L; ++ll) m = fmaxf(m, s[ll]);
    float sum = 0.f;
    #pragma unroll
    for (int ll = 0; ll < L; ++ll) { s[ll] = __expf(s[ll] - m); sum += s[ll]; }
    float inv = 1.f / sum;
    float outd = 0.f;
    #pragma unroll
    for (int ll = 0; ll < L; ++ll)
        outd = fmaf(s[ll] * inv, V[((size_t)r * KV_STRIDE + ll) * HID + lane], outd);

    atomicAdd(&acc[(size_t)c * HID + lane], nrm * outd);
}

// ---------- relu + store into x_all layer L ----------
__global__ void relu_store_kernel(const float* __restrict__ acc, float* __restrict__ x_all,
                                  int n, int L) {
    int t = blockIdx.x * blockDim.x + threadIdx.x;
    int node = t >> 6, d = t & 63;
    if (node >= n) return;
    x_all[(size_t)node * (MAXL * HID) + L * HID + d] = fmaxf(acc[(size_t)node * HID + d], 0.f);
}

// ---------- final: logits = x_all[:,3] @ W2 + b2; log_softmax over 32 classes ----------
__global__ void final_kernel(const float* __restrict__ x_all, const float* __restrict__ w2,
                             const float* __restrict__ b2, float* __restrict__ out, int n) {
    int t = blockIdx.x * blockDim.x + threadIdx.x;
    int node = t >> 5;
    int o = t & 31;
    if (node >= n) return;
    const float* xr = x_all + (size_t)node * (MAXL * HID) + 3 * HID;
    float logit = b2[o];
    #pragma unroll
    for (int d = 0; d < HID; ++d) logit = fmaf(xr[d], w2[d * N_CLASS + o], logit);
    float m = logit;
    for (int off = 16; off; off >>= 1) m = fmaxf(m, __shfl_xor(m, off, 32));
    float e = expf(logit - m);
    float sum = e;
    for (int off = 16; off; off >>= 1) sum += __shfl_xor(sum, off, 32);
    out[(size_t)node * N_CLASS + o] = (logit - m) - logf(sum);
}

extern "C" void kernel_launch(void* const* d_in, const int* in_sizes, int n_in,
                              void* d_out, int out_size, void* d_ws, size_t ws_size,
                              hipStream_t stream) {
    const float* x      = (const float*)d_in[0];
    const int*   eidx   = (const int*)d_in[1];     // (2, E): row=eidx[e], col=eidx[E+e]
    const float* lin1_w = (const float*)d_in[2];
    const float* lin1_b = (const float*)d_in[3];
    const float* wq     = (const float*)d_in[4];   // (3, 8, 8, 8)
    const float* bq     = (const float*)d_in[5];   // (3, 64)
    const float* wk     = (const float*)d_in[6];
    const float* bk     = (const float*)d_in[7];
    const float* wv     = (const float*)d_in[8];
    const float* bv     = (const float*)d_in[9];
    const float* lin2_w = (const float*)d_in[10];  // (64, 32)
    const float* lin2_b = (const float*)d_in[11];
    float* out = (float*)d_out;

    const int n  = NN;
    const int E  = NE;
    const int Ee = NE + NN;
    const int* row = eidx;
    const int* col = eidx + E;

    // workspace layout (all 256B aligned by construction)
    char* ws = (char*)d_ws;
    float* x_all = (float*)ws;                       ws += (size_t)NN * MAXL * HID * 4;   // 25.6 MB
    float* Q     = (float*)ws;                       ws += (size_t)NN * HID * 4;          // 6.4 MB
    float* K     = (float*)ws;                       ws += (size_t)NN * KV_STRIDE * HID * 4; // 19.2 MB
    float* V     = (float*)ws;                       ws += (size_t)NN * KV_STRIDE * HID * 4; // 19.2 MB
    float* acc   = (float*)ws;                       ws += (size_t)NN * HID * 4;          // 6.4 MB
    float* dis   = (float*)ws;                       ws += (size_t)NN * 4;
    int*   deg   = (int*)ws;                         ws += (size_t)NN * 4;

    // 1. degree + norm
    hipMemsetAsync(deg, 0, (size_t)NN * 4, stream);
    deg_kernel<<<(E + 255) / 256, 256, 0, stream>>>(col, deg, E);
    dis_kernel<<<(n + 255) / 256, 256, 0, stream>>>(deg, dis, n);

    // 2. lin1 -> x_all layer 0
    lin1_kernel<<<(n + 3) / 4, 256, 0, stream>>>(x, lin1_w, lin1_b, x_all, n);

    // 3. three DNA conv layers
    for (int l = 0; l < 3; ++l) {
        int L = l + 1;
        transform_kernel<<<(n * HID + 255) / 256, 256, 0, stream>>>(
            x_all, wq + l * 512, bq + l * 64, wk + l * 512, bk + l * 64,
            wv + l * 512, bv + l * 64, Q, K, V, n, L);
        hipMemsetAsync(acc, 0, (size_t)NN * HID * 4, stream);
        int blocks = (Ee + 3) / 4;   // 4 waves (edges) per 256-thread block
        if (L == 1)      edge_kernel<1><<<blocks, 256, 0, stream>>>(row, col, dis, Q, K, V, acc, E, Ee);
        else if (L == 2) edge_kernel<2><<<blocks, 256, 0, stream>>>(row, col, dis, Q, K, V, acc, E, Ee);
        else             edge_kernel<3><<<blocks, 256, 0, stream>>>(row, col, dis, Q, K, V, acc, E, Ee);
        relu_store_kernel<<<(n * HID + 255) / 256, 256, 0, stream>>>(acc, x_all, n, L);
    }

    // 4. classifier + log_softmax
    final_kernel<<<(n * N_CLASS + 255) / 256, 256, 0, stream>>>(x_all, lin2_w, lin2_b, out, n);
}

// Round 2
// 431.577 us; speedup vs baseline: 1.2855x; 1.2855x over previous
//
#include <hip/hip_runtime.h>
#include <hip/hip_fp16.h>
#include <math.h>

#define NN 25000
#define NE 400000
#define HID 64
#define F_IN 256
#define N_CLASS 32
#define MAXL 4          // x_all stores up to 4 layer slices
#define KV_STRIDE 3     // K/V layer stride (max 3 layers)

// ---------- degree ----------
__global__ void deg_kernel(const int* __restrict__ col, int* __restrict__ deg, int E) {
    int e = blockIdx.x * blockDim.x + threadIdx.x;
    if (e < E) atomicAdd(&deg[col[e]], 1);
}

__global__ void dis_kernel(const int* __restrict__ deg, float* __restrict__ dis, int n) {
    int i = blockIdx.x * blockDim.x + threadIdx.x;
    if (i < n) dis[i] = rsqrtf((float)(deg[i] + 1));  // +1 self loop; always > 0
}

// ---------- exclusive scan of deg -> rowptr (and cursor copy), single block ----------
__global__ void scan_kernel(const int* __restrict__ deg, int* __restrict__ rowptr,
                            int* __restrict__ cursor, int n) {
    __shared__ int sums[1024];
    int t = threadIdx.x;
    int chunk = (n + 1023) / 1024;
    int beg = t * chunk, end = min(beg + chunk, n);
    int s = 0;
    for (int i = beg; i < end; ++i) s += deg[i];
    sums[t] = s;
    __syncthreads();
    // Hillis-Steele inclusive scan in LDS
    for (int off = 1; off < 1024; off <<= 1) {
        int v = (t >= off) ? sums[t - off] : 0;
        __syncthreads();
        sums[t] += v;
        __syncthreads();
    }
    int run = sums[t] - s;   // exclusive base for this chunk
    for (int i = beg; i < end; ++i) {
        rowptr[i] = run;
        cursor[i] = run;
        run += deg[i];
    }
}

// ---------- scatter edges into CSR (grouped by destination col) ----------
__global__ void scatter_kernel(const int* __restrict__ row, const int* __restrict__ col,
                               int* __restrict__ cursor, int* __restrict__ csr_src, int E) {
    int e = blockIdx.x * blockDim.x + threadIdx.x;
    if (e >= E) return;
    int c = col[e];
    int p = atomicAdd(&cursor[c], 1);
    csr_src[p] = row[e];
}

// ---------- lin1: h = relu(x @ W1 + b1), write into x_all layer 0 ----------
__global__ void lin1_kernel(const float* __restrict__ x, const float* __restrict__ w,
                            const float* __restrict__ b, float* __restrict__ x_all, int n) {
    __shared__ float xs[4][F_IN];
    int n0 = blockIdx.x * 4;
    int t = threadIdx.x;
    #pragma unroll
    for (int i = 0; i < 4; ++i) {
        int node = n0 + i;
        xs[i][t] = (node < n) ? x[(size_t)node * F_IN + t] : 0.f;
    }
    __syncthreads();
    int i = t >> 6, o = t & 63;
    int node = n0 + i;
    if (node >= n) return;
    float acc = b[o];
    for (int k = 0; k < F_IN; ++k) acc = fmaf(xs[i][k], w[k * HID + o], acc);
    x_all[(size_t)node * (MAXL * HID) + o] = fmaxf(acc, 0.f);
}

// ---------- per-node q/k/v grouped-linear transform (K/V stored fp16) ----------
// grouped_linear: out[d] = b[d] + sum_i x[g*8+i] * w[g*64 + i*8 + o], g=d>>3, o=d&7
__global__ void transform_kernel(const float* __restrict__ x_all,
                                 const float* __restrict__ wq, const float* __restrict__ bq,
                                 const float* __restrict__ wk, const float* __restrict__ bk,
                                 const float* __restrict__ wv, const float* __restrict__ bv,
                                 float* __restrict__ Q, __half* __restrict__ K,
                                 __half* __restrict__ V, int n, int L) {
    int t = blockIdx.x * blockDim.x + threadIdx.x;
    int node = t >> 6, d = t & 63;
    if (node >= n) return;
    int g = d >> 3, o = d & 7;
    const float* xrow = x_all + (size_t)node * (MAXL * HID);

    {   // Q from last layer (L-1), kept fp32
        const float* xg = xrow + (L - 1) * HID + g * 8;
        const float* wg = wq + g * 64 + o;
        float acc = bq[d];
        #pragma unroll
        for (int i = 0; i < 8; ++i) acc = fmaf(xg[i], wg[i * 8], acc);
        Q[(size_t)node * HID + d] = acc;
    }
    for (int ll = 0; ll < L; ++ll) {
        const float* xg = xrow + ll * HID + g * 8;
        const float* wgk = wk + g * 64 + o;
        const float* wgv = wv + g * 64 + o;
        float ak = bk[d], av = bv[d];
        #pragma unroll
        for (int i = 0; i < 8; ++i) {
            ak = fmaf(xg[i], wgk[i * 8], ak);
            av = fmaf(xg[i], wgv[i * 8], av);
        }
        K[((size_t)node * KV_STRIDE + ll) * HID + d] = __float2half(ak);
        V[((size_t)node * KV_STRIDE + ll) * HID + d] = __float2half(av);
    }
}

// ---------- gather + attend: one wave64 per destination node ----------
// lane = output dim d; head = d>>3. Accumulate over in-edges + self loop in registers.
template <int L>
__device__ __forceinline__ float edge_contrib(float q, int r, float nrm, int lane,
                                              const __half* __restrict__ K,
                                              const __half* __restrict__ V) {
    float kk[L], vv[L];
    #pragma unroll
    for (int ll = 0; ll < L; ++ll) {
        kk[ll] = __half2float(K[((size_t)r * KV_STRIDE + ll) * HID + lane]);
        vv[ll] = __half2float(V[((size_t)r * KV_STRIDE + ll) * HID + lane]);
    }
    float s[L];
    #pragma unroll
    for (int ll = 0; ll < L; ++ll) {
        float p = q * kk[ll];
        p += __shfl_xor(p, 1);   // reduce within 8-lane head group
        p += __shfl_xor(p, 2);
        p += __shfl_xor(p, 4);
        s[ll] = p * 0.35355339059327373f;   // 1/sqrt(8)
    }
    float m = s[0];
    #pragma unroll
    for (int ll = 1; ll < L; ++ll) m = fmaxf(m, s[ll]);
    float sum = 0.f;
    #pragma unroll
    for (int ll = 0; ll < L; ++ll) { s[ll] = __expf(s[ll] - m); sum += s[ll]; }
    float inv = 1.f / sum;
    float outd = 0.f;
    #pragma unroll
    for (int ll = 0; ll < L; ++ll) outd = fmaf(s[ll] * inv, vv[ll], outd);
    return nrm * outd;
}

template <int L>
__global__ void gather_kernel(const int* __restrict__ rowptr, const int* __restrict__ deg,
                              const int* __restrict__ csr_src, const float* __restrict__ dis,
                              const float* __restrict__ Q, const __half* __restrict__ K,
                              const __half* __restrict__ V, float* __restrict__ x_all, int n) {
    int wave = (int)((blockIdx.x * (size_t)blockDim.x + threadIdx.x) >> 6);
    int lane = threadIdx.x & 63;
    if (wave >= n) return;
    int c = wave;
    float q = Q[(size_t)c * HID + lane];
    float nc = dis[c];
    // self loop
    float acc = edge_contrib<L>(q, c, nc * nc, lane, K, V);
    int beg = rowptr[c];
    int end = beg + deg[c];
    int j = beg;
    // 2-wide unroll for memory-level parallelism
    for (; j + 1 < end; j += 2) {
        int r0 = csr_src[j], r1 = csr_src[j + 1];
        float a0 = edge_contrib<L>(q, r0, nc * dis[r0], lane, K, V);
        float a1 = edge_contrib<L>(q, r1, nc * dis[r1], lane, K, V);
        acc += a0 + a1;
    }
    if (j < end) {
        int r0 = csr_src[j];
        acc += edge_contrib<L>(q, r0, nc * dis[r0], lane, K, V);
    }
    x_all[(size_t)c * (MAXL * HID) + L * HID + lane] = fmaxf(acc, 0.f);
}

// ---------- final: logits = x_all[:,3] @ W2 + b2; log_softmax over 32 classes ----------
__global__ void final_kernel(const float* __restrict__ x_all, const float* __restrict__ w2,
                             const float* __restrict__ b2, float* __restrict__ out, int n) {
    int t = blockIdx.x * blockDim.x + threadIdx.x;
    int node = t >> 5;
    int o = t & 31;
    if (node >= n) return;
    const float* xr = x_all + (size_t)node * (MAXL * HID) + 3 * HID;
    float logit = b2[o];
    #pragma unroll
    for (int d = 0; d < HID; ++d) logit = fmaf(xr[d], w2[d * N_CLASS + o], logit);
    float m = logit;
    for (int off = 16; off; off >>= 1) m = fmaxf(m, __shfl_xor(m, off, 32));
    float e = expf(logit - m);
    float sum = e;
    for (int off = 16; off; off >>= 1) sum += __shfl_xor(sum, off, 32);
    out[(size_t)node * N_CLASS + o] = (logit - m) - logf(sum);
}

extern "C" void kernel_launch(void* const* d_in, const int* in_sizes, int n_in,
                              void* d_out, int out_size, void* d_ws, size_t ws_size,
                              hipStream_t stream) {
    const float* x      = (const float*)d_in[0];
    const int*   eidx   = (const int*)d_in[1];     // (2, E): row=eidx[e], col=eidx[E+e]
    const float* lin1_w = (const float*)d_in[2];
    const float* lin1_b = (const float*)d_in[3];
    const float* wq     = (const float*)d_in[4];   // (3, 8, 8, 8)
    const float* bq     = (const float*)d_in[5];   // (3, 64)
    const float* wk     = (const float*)d_in[6];
    const float* bk     = (const float*)d_in[7];
    const float* wv     = (const float*)d_in[8];
    const float* bv     = (const float*)d_in[9];
    const float* lin2_w = (const float*)d_in[10];  // (64, 32)
    const float* lin2_b = (const float*)d_in[11];
    float* out = (float*)d_out;

    const int n  = NN;
    const int E  = NE;
    const int* row = eidx;
    const int* col = eidx + E;

    // workspace layout
    char* ws = (char*)d_ws;
    float*  x_all  = (float*)ws;   ws += (size_t)NN * MAXL * HID * 4;       // 25.6 MB
    float*  Q      = (float*)ws;   ws += (size_t)NN * HID * 4;              // 6.4 MB
    __half* K      = (__half*)ws;  ws += (size_t)NN * KV_STRIDE * HID * 2;  // 9.6 MB
    __half* V      = (__half*)ws;  ws += (size_t)NN * KV_STRIDE * HID * 2;  // 9.6 MB
    float*  dis    = (float*)ws;   ws += (size_t)NN * 4;
    int*    deg    = (int*)ws;     ws += (size_t)NN * 4;
    int*    rowptr = (int*)ws;     ws += (size_t)NN * 4;
    int*    cursor = (int*)ws;     ws += (size_t)NN * 4;
    int*    csr    = (int*)ws;     ws += (size_t)NE * 4;                    // 1.6 MB

    // 1. degree + norm + CSR build
    hipMemsetAsync(deg, 0, (size_t)NN * 4, stream);
    deg_kernel<<<(E + 255) / 256, 256, 0, stream>>>(col, deg, E);
    dis_kernel<<<(n + 255) / 256, 256, 0, stream>>>(deg, dis, n);
    scan_kernel<<<1, 1024, 0, stream>>>(deg, rowptr, cursor, n);
    scatter_kernel<<<(E + 255) / 256, 256, 0, stream>>>(row, col, cursor, csr, E);

    // 2. lin1 -> x_all layer 0
    lin1_kernel<<<(n + 3) / 4, 256, 0, stream>>>(x, lin1_w, lin1_b, x_all, n);

    // 3. three DNA conv layers
    for (int l = 0; l < 3; ++l) {
        int L = l + 1;
        transform_kernel<<<(n * HID + 255) / 256, 256, 0, stream>>>(
            x_all, wq + l * 512, bq + l * 64, wk + l * 512, bk + l * 64,
            wv + l * 512, bv + l * 64, Q, K, V, n, L);
        int blocks = (n + 3) / 4;   // 4 nodes (waves) per 256-thread block
        if (L == 1)      gather_kernel<1><<<blocks, 256, 0, stream>>>(rowptr, deg, csr, dis, Q, K, V, x_all, n);
        else if (L == 2) gather_kernel<2><<<blocks, 256, 0, stream>>>(rowptr, deg, csr, dis, Q, K, V, x_all, n);
        else             gather_kernel<3><<<blocks, 256, 0, stream>>>(rowptr, deg, csr, dis, Q, K, V, x_all, n);
    }

    // 4. classifier + log_softmax
    final_kernel<<<(n * N_CLASS + 255) / 256, 256, 0, stream>>>(x_all, lin2_w, lin2_b, out, n);
}

// Round 3
// 386.383 us; speedup vs baseline: 1.4359x; 1.1170x over previous
//
#include <hip/hip_runtime.h>
#include <hip/hip_fp16.h>
#include <math.h>

#define NN 25000
#define NE 400000
#define HID 64
#define F_IN 256
#define N_CLASS 32
#define MAXL 4          // x_all stores up to 4 layer slices
#define KVS 3           // K/V layer slots

typedef _Float16 f16;
typedef _Float16 f16x2 __attribute__((ext_vector_type(2)));
typedef _Float16 f16x8 __attribute__((ext_vector_type(8)));

union F16x8 {
    f16x8 v;
    f16x2 h[4];
    __half2 hh[4];
};

__device__ __forceinline__ float dot2(f16x2 a, f16x2 b, float c) {
#if __has_builtin(__builtin_amdgcn_fdot2)
    return __builtin_amdgcn_fdot2(a, b, c, false);
#else
    return c + (float)a[0] * (float)b[0] + (float)a[1] * (float)b[1];
#endif
}

// ---------- degree / norm ----------
__global__ void deg_kernel(const int* __restrict__ col, int* __restrict__ deg, int E) {
    int e = blockIdx.x * blockDim.x + threadIdx.x;
    if (e < E) atomicAdd(&deg[col[e]], 1);
}

__global__ void dis_kernel(const int* __restrict__ deg, float* __restrict__ dis, int n) {
    int i = blockIdx.x * blockDim.x + threadIdx.x;
    if (i < n) dis[i] = rsqrtf((float)(deg[i] + 1));  // +1 self loop; always > 0
}

// ---------- exclusive scan of deg -> rowptr (and cursor copy), single block ----------
__global__ void scan_kernel(const int* __restrict__ deg, int* __restrict__ rowptr,
                            int* __restrict__ cursor, int n) {
    __shared__ int sums[1024];
    int t = threadIdx.x;
    int chunk = (n + 1023) / 1024;
    int beg = t * chunk, end = min(beg + chunk, n);
    int s = 0;
    for (int i = beg; i < end; ++i) s += deg[i];
    sums[t] = s;
    __syncthreads();
    for (int off = 1; off < 1024; off <<= 1) {
        int v = (t >= off) ? sums[t - off] : 0;
        __syncthreads();
        sums[t] += v;
        __syncthreads();
    }
    int run = sums[t] - s;   // exclusive base for this chunk
    for (int i = beg; i < end; ++i) {
        rowptr[i] = run;
        cursor[i] = run;
        run += deg[i];
    }
}

// ---------- scatter edges into CSR (grouped by destination col) ----------
__global__ void scatter_kernel(const int* __restrict__ row, const int* __restrict__ col,
                               int* __restrict__ cursor, int* __restrict__ csr_src, int E) {
    int e = blockIdx.x * blockDim.x + threadIdx.x;
    if (e >= E) return;
    int c = col[e];
    int p = atomicAdd(&cursor[c], 1);
    csr_src[p] = row[e];
}

// ---------- lin1: h = relu(x @ W1 + b1), write into x_all layer 0 ----------
__global__ void lin1_kernel(const float* __restrict__ x, const float* __restrict__ w,
                            const float* __restrict__ b, float* __restrict__ x_all, int n) {
    __shared__ float xs[4][F_IN];
    int n0 = blockIdx.x * 4;
    int t = threadIdx.x;
    #pragma unroll
    for (int i = 0; i < 4; ++i) {
        int node = n0 + i;
        xs[i][t] = (node < n) ? x[(size_t)node * F_IN + t] : 0.f;
    }
    __syncthreads();
    int i = t >> 6, o = t & 63;
    int node = n0 + i;
    if (node >= n) return;
    float acc = b[o];
    #pragma unroll 8
    for (int k = 0; k < F_IN; ++k) acc = fmaf(xs[i][k], w[k * HID + o], acc);
    x_all[(size_t)node * (MAXL * HID) + o] = fmaxf(acc, 0.f);
}

// ---------- per-node q/k/v grouped-linear transform (fp16-packed outputs) ----------
// out[d] = b[d] + sum_i x[g*8+i] * w[g*64 + i*8 + o], g=d>>3, o=d&7
// thread u in [0,32) per node handles dim pair {2u, 2u+1}
// KV layout: f16x2[((node*KVS + ll)*2 + kv)*32 + u]  -> per-node contiguous 768B
__global__ void transform_kernel(const float* __restrict__ x_all,
                                 const float* __restrict__ wq, const float* __restrict__ bq,
                                 const float* __restrict__ wk, const float* __restrict__ bk,
                                 const float* __restrict__ wv, const float* __restrict__ bv,
                                 f16x2* __restrict__ Q2, f16x2* __restrict__ KV,
                                 int n, int L) {
    int t = blockIdx.x * blockDim.x + threadIdx.x;
    int node = t >> 5, u = t & 31;
    if (node >= n) return;
    int g = u >> 2;               // head/group of both dims
    int o0 = (u & 3) * 2;         // within-group output index of dim 2u
    const float* xrow = x_all + (size_t)node * (MAXL * HID);

    {   // Q from layer L-1
        const float* xg = xrow + (L - 1) * HID + g * 8;
        const float* wg = wq + g * 64;
        float a0 = bq[g * 8 + o0], a1 = bq[g * 8 + o0 + 1];
        #pragma unroll
        for (int i = 0; i < 8; ++i) {
            float xv = xg[i];
            a0 = fmaf(xv, wg[i * 8 + o0], a0);
            a1 = fmaf(xv, wg[i * 8 + o0 + 1], a1);
        }
        f16x2 q; q[0] = (f16)a0; q[1] = (f16)a1;
        Q2[(size_t)node * 32 + u] = q;
    }
    for (int ll = 0; ll < L; ++ll) {
        const float* xg = xrow + ll * HID + g * 8;
        const float* wgk = wk + g * 64;
        const float* wgv = wv + g * 64;
        float k0 = bk[g * 8 + o0], k1 = bk[g * 8 + o0 + 1];
        float v0 = bv[g * 8 + o0], v1 = bv[g * 8 + o0 + 1];
        #pragma unroll
        for (int i = 0; i < 8; ++i) {
            float xv = xg[i];
            k0 = fmaf(xv, wgk[i * 8 + o0], k0);
            k1 = fmaf(xv, wgk[i * 8 + o0 + 1], k1);
            v0 = fmaf(xv, wgv[i * 8 + o0], v0);
            v1 = fmaf(xv, wgv[i * 8 + o0 + 1], v1);
        }
        f16x2 kh; kh[0] = (f16)k0; kh[1] = (f16)k1;
        f16x2 vh; vh[0] = (f16)v0; vh[1] = (f16)v1;
        size_t base = ((size_t)node * KVS + ll) * 2;
        KV[(base + 0) * 32 + u] = kh;
        KV[(base + 1) * 32 + u] = vh;
    }
}

// ---------- gather + attend: one wave64 per destination, 8 edges per wave ----------
// lane = (slot 0..7) * 8 + head; each lane holds its head's full 8 dims (b128 fp16).
// Virtual edge list per node c: [self] + csr[beg .. beg+deg). Invalid slots get nrm=0.
template <int L>
__global__ void gather_kernel(const int* __restrict__ rowptr, const int* __restrict__ deg,
                              const int* __restrict__ csr_src, const float* __restrict__ dis,
                              const f16x8* __restrict__ Q8, const f16x8* __restrict__ KV8,
                              float* __restrict__ x_all, int n) {
    int wave = (int)((blockIdx.x * (size_t)blockDim.x + threadIdx.x) >> 6);
    int lane = threadIdx.x & 63;
    if (wave >= n) return;
    int c = wave;
    int u = lane & 7;         // head
    int slot = lane >> 3;     // edge slot
    F16x8 q; q.v = Q8[(size_t)c * 8 + u];
    float nc = dis[c];
    int beg = rowptr[c];
    int dc = deg[c] + 1;      // + self loop
    float acc[8];
    #pragma unroll
    for (int i = 0; i < 8; ++i) acc[i] = 0.f;

    for (int j = 0; j < dc; j += 8) {
        int jj = j + slot;
        bool valid = jj < dc;
        int r = c;
        if (valid && jj > 0) r = csr_src[beg + jj - 1];
        float nrm = valid ? nc * dis[r] : 0.f;

        F16x8 kk[L], vv[L];
        size_t rb = (size_t)r * (KVS * 2 * 8);   // f16x8 units per node = 48
        #pragma unroll
        for (int ll = 0; ll < L; ++ll) {
            kk[ll].v = KV8[rb + ll * 16 + u];
            vv[ll].v = KV8[rb + ll * 16 + 8 + u];
        }
        float s[L];
        #pragma unroll
        for (int ll = 0; ll < L; ++ll) {
            float p = 0.f;
            #pragma unroll
            for (int i2 = 0; i2 < 4; ++i2) p = dot2(q.h[i2], kk[ll].h[i2], p);
            s[ll] = p * 0.35355339059327373f;   // 1/sqrt(8)
        }
        float m = s[0];
        #pragma unroll
        for (int ll = 1; ll < L; ++ll) m = fmaxf(m, s[ll]);
        float sum = 0.f;
        #pragma unroll
        for (int ll = 0; ll < L; ++ll) { s[ll] = __expf(s[ll] - m); sum += s[ll]; }
        float inv = nrm / sum;                   // fold norm into probs

        __half2 ha[4];
        #pragma unroll
        for (int i2 = 0; i2 < 4; ++i2) ha[i2] = __float2half2_rn(0.f);
        #pragma unroll
        for (int ll = 0; ll < L; ++ll) {
            __half2 p2 = __float2half2_rn(s[ll] * inv);
            #pragma unroll
            for (int i2 = 0; i2 < 4; ++i2) ha[i2] = __hfma2(p2, vv[ll].hh[i2], ha[i2]);
        }
        #pragma unroll
        for (int i2 = 0; i2 < 4; ++i2) {
            float2 f = __half22float2(ha[i2]);
            acc[i2 * 2]     += f.x;
            acc[i2 * 2 + 1] += f.y;
        }
    }
    // reduce the 8 edge slots (once per node)
    #pragma unroll
    for (int off = 8; off < 64; off <<= 1) {
        #pragma unroll
        for (int i = 0; i < 8; ++i) acc[i] += __shfl_xor(acc[i], off);
    }
    if (slot == 0) {
        float4* dst = (float4*)(x_all + ((size_t)c * MAXL + L) * HID + u * 8);
        dst[0] = make_float4(fmaxf(acc[0], 0.f), fmaxf(acc[1], 0.f),
                             fmaxf(acc[2], 0.f), fmaxf(acc[3], 0.f));
        dst[1] = make_float4(fmaxf(acc[4], 0.f), fmaxf(acc[5], 0.f),
                             fmaxf(acc[6], 0.f), fmaxf(acc[7], 0.f));
    }
}

// ---------- final: logits = x_all[:,3] @ W2 + b2; log_softmax over 32 classes ----------
__global__ void final_kernel(const float* __restrict__ x_all, const float* __restrict__ w2,
                             const float* __restrict__ b2, float* __restrict__ out, int n) {
    int t = blockIdx.x * blockDim.x + threadIdx.x;
    int node = t >> 5;
    int o = t & 31;
    if (node >= n) return;
    const float* xr = x_all + (size_t)node * (MAXL * HID) + 3 * HID;
    float logit = b2[o];
    #pragma unroll
    for (int d = 0; d < HID; ++d) logit = fmaf(xr[d], w2[d * N_CLASS + o], logit);
    float m = logit;
    for (int off = 16; off; off >>= 1) m = fmaxf(m, __shfl_xor(m, off, 32));
    float e = expf(logit - m);
    float sum = e;
    for (int off = 16; off; off >>= 1) sum += __shfl_xor(sum, off, 32);
    out[(size_t)node * N_CLASS + o] = (logit - m) - logf(sum);
}

extern "C" void kernel_launch(void* const* d_in, const int* in_sizes, int n_in,
                              void* d_out, int out_size, void* d_ws, size_t ws_size,
                              hipStream_t stream) {
    const float* x      = (const float*)d_in[0];
    const int*   eidx   = (const int*)d_in[1];     // (2, E)
    const float* lin1_w = (const float*)d_in[2];
    const float* lin1_b = (const float*)d_in[3];
    const float* wq     = (const float*)d_in[4];   // (3, 8, 8, 8)
    const float* bq     = (const float*)d_in[5];   // (3, 64)
    const float* wk     = (const float*)d_in[6];
    const float* bk     = (const float*)d_in[7];
    const float* wv     = (const float*)d_in[8];
    const float* bv     = (const float*)d_in[9];
    const float* lin2_w = (const float*)d_in[10];  // (64, 32)
    const float* lin2_b = (const float*)d_in[11];
    float* out = (float*)d_out;

    const int n  = NN;
    const int E  = NE;
    const int* row = eidx;
    const int* col = eidx + E;

    // workspace layout (16B-aligned where vector-accessed)
    char* ws = (char*)d_ws;
    float*  x_all  = (float*)ws;   ws += (size_t)NN * MAXL * HID * 4;        // 25.6 MB
    f16x2*  Q2     = (f16x2*)ws;   ws += (size_t)NN * 32 * 4;                // 3.2 MB
    f16x2*  KV     = (f16x2*)ws;   ws += (size_t)NN * KVS * 2 * 32 * 4;      // 19.2 MB
    float*  dis    = (float*)ws;   ws += (size_t)NN * 4;
    int*    deg    = (int*)ws;     ws += (size_t)NN * 4;
    int*    rowptr = (int*)ws;     ws += (size_t)NN * 4;
    int*    cursor = (int*)ws;     ws += (size_t)NN * 4;
    int*    csr    = (int*)ws;     ws += (size_t)NE * 4;                     // 1.6 MB

    // 1. degree + norm + CSR build
    hipMemsetAsync(deg, 0, (size_t)NN * 4, stream);
    deg_kernel<<<(E + 255) / 256, 256, 0, stream>>>(col, deg, E);
    dis_kernel<<<(n + 255) / 256, 256, 0, stream>>>(deg, dis, n);
    scan_kernel<<<1, 1024, 0, stream>>>(deg, rowptr, cursor, n);
    scatter_kernel<<<(E + 255) / 256, 256, 0, stream>>>(row, col, cursor, csr, E);

    // 2. lin1 -> x_all layer 0
    lin1_kernel<<<(n + 3) / 4, 256, 0, stream>>>(x, lin1_w, lin1_b, x_all, n);

    // 3. three DNA conv layers
    for (int l = 0; l < 3; ++l) {
        int L = l + 1;
        transform_kernel<<<(n * 32 + 255) / 256, 256, 0, stream>>>(
            x_all, wq + l * 512, bq + l * 64, wk + l * 512, bk + l * 64,
            wv + l * 512, bv + l * 64, Q2, KV, n, L);
        int blocks = (n + 3) / 4;   // 4 nodes (waves) per 256-thread block
        if (L == 1)      gather_kernel<1><<<blocks, 256, 0, stream>>>(rowptr, deg, csr, dis, (const f16x8*)Q2, (const f16x8*)KV, x_all, n);
        else if (L == 2) gather_kernel<2><<<blocks, 256, 0, stream>>>(rowptr, deg, csr, dis, (const f16x8*)Q2, (const f16x8*)KV, x_all, n);
        else             gather_kernel<3><<<blocks, 256, 0, stream>>>(rowptr, deg, csr, dis, (const f16x8*)Q2, (const f16x8*)KV, x_all, n);
    }

    // 4. classifier + log_softmax
    final_kernel<<<(n * N_CLASS + 255) / 256, 256, 0, stream>>>(x_all, lin2_w, lin2_b, out, n);
}

// Round 5
// 344.078 us; speedup vs baseline: 1.6125x; 1.1230x over previous
//
#include <hip/hip_runtime.h>
#include <hip/hip_fp16.h>
#include <math.h>

#define NN 25000
#define NE 400000
#define HID 64
#define F_IN 256
#define N_CLASS 32
#define MAXL 4          // x_all stores up to 4 layer slices
#define KVS 3           // K/V layer slots
#define WPAD 264        // f16 row stride of W^T in LDS (256 + 8 pad -> 4-bank rotate)

typedef _Float16 f16;
typedef _Float16 f16x2 __attribute__((ext_vector_type(2)));
typedef _Float16 f16x8 __attribute__((ext_vector_type(8)));
typedef float f32x4 __attribute__((ext_vector_type(4)));

union F16x8 {
    f16x8 v;
    f16x2 h[4];
    __half2 hh[4];
};

__device__ __forceinline__ float dot2(f16x2 a, f16x2 b, float c) {
#if __has_builtin(__builtin_amdgcn_fdot2)
    return __builtin_amdgcn_fdot2(a, b, c, false);
#else
    return c + (float)a[0] * (float)b[0] + (float)a[1] * (float)b[1];
#endif
}

// ---------- degree / norm ----------
__global__ void deg_kernel(const int* __restrict__ col, int* __restrict__ deg, int E) {
    int e = blockIdx.x * blockDim.x + threadIdx.x;
    if (e < E) atomicAdd(&deg[col[e]], 1);
}

__global__ void dis_kernel(const int* __restrict__ deg, float* __restrict__ dis, int n) {
    int i = blockIdx.x * blockDim.x + threadIdx.x;
    if (i < n) dis[i] = rsqrtf((float)(deg[i] + 1));  // +1 self loop; always > 0
}

// ---------- exclusive scan of deg -> rowptr (and cursor copy), single block ----------
__global__ void scan_kernel(const int* __restrict__ deg, int* __restrict__ rowptr,
                            int* __restrict__ cursor, int n) {
    __shared__ int sums[1024];
    int t = threadIdx.x;
    int chunk = (n + 1023) / 1024;
    int beg = t * chunk, end = min(beg + chunk, n);
    int s = 0;
    for (int i = beg; i < end; ++i) s += deg[i];
    sums[t] = s;
    __syncthreads();
    for (int off = 1; off < 1024; off <<= 1) {
        int v = (t >= off) ? sums[t - off] : 0;
        __syncthreads();
        sums[t] += v;
        __syncthreads();
    }
    int run = sums[t] - s;   // exclusive base for this chunk
    for (int i = beg; i < end; ++i) {
        rowptr[i] = run;
        cursor[i] = run;
        run += deg[i];
    }
}

// ---------- scatter edges into CSR (grouped by destination col) ----------
__global__ void scatter_kernel(const int* __restrict__ row, const int* __restrict__ col,
                               int* __restrict__ cursor, int* __restrict__ csr_src, int E) {
    int e = blockIdx.x * blockDim.x + threadIdx.x;
    if (e >= E) return;
    int c = col[e];
    int p = atomicAdd(&cursor[c], 1);
    csr_src[p] = row[e];
}

// ---------- W1 -> fp16 transposed: wt[n][k] = (f16) w[k*64+n] ----------
__global__ void wprep_kernel(const float* __restrict__ w, f16* __restrict__ wt) {
    int e = blockIdx.x * blockDim.x + threadIdx.x;  // 16384 elements
    int k = e >> 6, nn = e & 63;
    wt[nn * F_IN + k] = (f16)w[e];
}

// ---------- lin1 via MFMA: h = relu(x @ W1 + b1) -> x_all layer 0 ----------
// Block: 256 thr = 4 waves; each wave one 16-row M-tile, N=64 (4 n-subtiles).
// A[m=lane&15][k=quad*8+j] from global fp32 x (cvt), B[n=lane&15][k=quad*8+j] from LDS W^T.
__global__ void __launch_bounds__(256) lin1_mfma_kernel(
        const float* __restrict__ x, const f16x8* __restrict__ wt,
        const float* __restrict__ b, float* __restrict__ x_all, int n) {
    __shared__ f16 wlds[64 * WPAD];
    int t = threadIdx.x;
    #pragma unroll
    for (int j = 0; j < 8; ++j) {                 // stage all 2048 f16x8 units (32 KB)
        int idx = t + j * 256;                    // f16x8 unit index
        int e = idx * 8;
        int nr = e >> 8, k0 = e & 255;
        *(f16x8*)&wlds[nr * WPAD + k0] = wt[idx];
    }
    __syncthreads();
    int wave = t >> 6, lane = t & 63;
    int m = lane & 15, quad = lane >> 4;
    int rowA = blockIdx.x * 64 + wave * 16 + m;
    int rA = min(rowA, n - 1);                    // clamp; masked at store
    const float* xp = x + (size_t)rA * F_IN + quad * 8;
    f32x4 acc[4] = {};
    for (int kk = 0; kk < F_IN; kk += 32) {
        float4 x0 = *(const float4*)(xp + kk);
        float4 x1 = *(const float4*)(xp + kk + 4);
        f16x8 a;
        a[0] = (f16)x0.x; a[1] = (f16)x0.y; a[2] = (f16)x0.z; a[3] = (f16)x0.w;
        a[4] = (f16)x1.x; a[5] = (f16)x1.y; a[6] = (f16)x1.z; a[7] = (f16)x1.w;
        #pragma unroll
        for (int nt = 0; nt < 4; ++nt) {
            f16x8 bf = *(const f16x8*)&wlds[(nt * 16 + m) * WPAD + kk + quad * 8];
            acc[nt] = __builtin_amdgcn_mfma_f32_16x16x32_f16(a, bf, acc[nt], 0, 0, 0);
        }
    }
    int rowC = blockIdx.x * 64 + wave * 16 + quad * 4;
    #pragma unroll
    for (int nt = 0; nt < 4; ++nt) {
        int col = nt * 16 + m;
        float bias = b[col];
        #pragma unroll
        for (int r = 0; r < 4; ++r) {
            int row = rowC + r;
            if (row < n)
                x_all[(size_t)row * (MAXL * HID) + col] = fmaxf(acc[nt][r] + bias, 0.f);
        }
    }
}

// ---------- per-node q/k/v grouped-linear transform (fp16-packed outputs) ----------
// out[d] = b[d] + sum_i x[g*8+i] * w[g*64 + i*8 + o], g=d>>3, o=d&7
// thread u in [0,32) per node handles dim pair {2u, 2u+1}
// KV layout: f16x2[((node*KVS + ll)*2 + kv)*32 + u]  -> per-node contiguous 768B
__global__ void transform_kernel(const float* __restrict__ x_all,
                                 const float* __restrict__ wq, const float* __restrict__ bq,
                                 const float* __restrict__ wk, const float* __restrict__ bk,
                                 const float* __restrict__ wv, const float* __restrict__ bv,
                                 f16x2* __restrict__ Q2, f16x2* __restrict__ KV,
                                 int n, int L) {
    int t = blockIdx.x * blockDim.x + threadIdx.x;
    int node = t >> 5, u = t & 31;
    if (node >= n) return;
    int g = u >> 2;               // head/group of both dims
    int o0 = (u & 3) * 2;         // within-group output index of dim 2u
    const float* xrow = x_all + (size_t)node * (MAXL * HID);

    {   // Q from layer L-1
        const float* xg = xrow + (L - 1) * HID + g * 8;
        const float* wg = wq + g * 64;
        float a0 = bq[g * 8 + o0], a1 = bq[g * 8 + o0 + 1];
        #pragma unroll
        for (int i = 0; i < 8; ++i) {
            float xv = xg[i];
            a0 = fmaf(xv, wg[i * 8 + o0], a0);
            a1 = fmaf(xv, wg[i * 8 + o0 + 1], a1);
        }
        f16x2 q; q[0] = (f16)a0; q[1] = (f16)a1;
        Q2[(size_t)node * 32 + u] = q;
    }
    for (int ll = 0; ll < L; ++ll) {
        const float* xg = xrow + ll * HID + g * 8;
        const float* wgk = wk + g * 64;
        const float* wgv = wv + g * 64;
        float k0 = bk[g * 8 + o0], k1 = bk[g * 8 + o0 + 1];
        float v0 = bv[g * 8 + o0], v1 = bv[g * 8 + o0 + 1];
        #pragma unroll
        for (int i = 0; i < 8; ++i) {
            float xv = xg[i];
            k0 = fmaf(xv, wgk[i * 8 + o0], k0);
            k1 = fmaf(xv, wgk[i * 8 + o0 + 1], k1);
            v0 = fmaf(xv, wgv[i * 8 + o0], v0);
            v1 = fmaf(xv, wgv[i * 8 + o0 + 1], v1);
        }
        f16x2 kh; kh[0] = (f16)k0; kh[1] = (f16)k1;
        f16x2 vh; vh[0] = (f16)v0; vh[1] = (f16)v1;
        size_t base = ((size_t)node * KVS + ll) * 2;
        KV[(base + 0) * 32 + u] = kh;
        KV[(base + 1) * 32 + u] = vh;
    }
}

// ---------- gather + attend: one wave64 per destination, 8 edges per wave ----------
template <int L>
__global__ void gather_kernel(const int* __restrict__ rowptr, const int* __restrict__ deg,
                              const int* __restrict__ csr_src, const float* __restrict__ dis,
                              const f16x8* __restrict__ Q8, const f16x8* __restrict__ KV8,
                              float* __restrict__ x_all, int n) {
    int wave = (int)((blockIdx.x * (size_t)blockDim.x + threadIdx.x) >> 6);
    int lane = threadIdx.x & 63;
    if (wave >= n) return;
    int c = wave;
    int u = lane & 7;         // head
    int slot = lane >> 3;     // edge slot
    F16x8 q; q.v = Q8[(size_t)c * 8 + u];
    float nc = dis[c];
    int beg = rowptr[c];
    int dc = deg[c] + 1;      // + self loop
    float acc[8];
    #pragma unroll
    for (int i = 0; i < 8; ++i) acc[i] = 0.f;

    for (int j = 0; j < dc; j += 8) {
        int jj = j + slot;
        bool valid = jj < dc;
        int r = c;
        if (valid && jj > 0) r = csr_src[beg + jj - 1];
        float nrm = valid ? nc * dis[r] : 0.f;

        F16x8 kk[L], vv[L];
        size_t rb = (size_t)r * (KVS * 2 * 8);   // f16x8 units per node = 48
        #pragma unroll
        for (int ll = 0; ll < L; ++ll) {
            kk[ll].v = KV8[rb + ll * 16 + u];
            vv[ll].v = KV8[rb + ll * 16 + 8 + u];
        }
        float s[L];
        #pragma unroll
        for (int ll = 0; ll < L; ++ll) {
            float p = 0.f;
            #pragma unroll
            for (int i2 = 0; i2 < 4; ++i2) p = dot2(q.h[i2], kk[ll].h[i2], p);
            s[ll] = p * 0.35355339059327373f;   // 1/sqrt(8)
        }
        float m = s[0];
        #pragma unroll
        for (int ll = 1; ll < L; ++ll) m = fmaxf(m, s[ll]);
        float sum = 0.f;
        #pragma unroll
        for (int ll = 0; ll < L; ++ll) { s[ll] = __expf(s[ll] - m); sum += s[ll]; }
        float inv = nrm / sum;                   // fold norm into probs

        __half2 ha[4];
        #pragma unroll
        for (int i2 = 0; i2 < 4; ++i2) ha[i2] = __float2half2_rn(0.f);
        #pragma unroll
        for (int ll = 0; ll < L; ++ll) {
            __half2 p2 = __float2half2_rn(s[ll] * inv);
            #pragma unroll
            for (int i2 = 0; i2 < 4; ++i2) ha[i2] = __hfma2(p2, vv[ll].hh[i2], ha[i2]);
        }
        #pragma unroll
        for (int i2 = 0; i2 < 4; ++i2) {
            float2 f = __half22float2(ha[i2]);
            acc[i2 * 2]     += f.x;
            acc[i2 * 2 + 1] += f.y;
        }
    }
    // reduce the 8 edge slots (once per node)
    #pragma unroll
    for (int off = 8; off < 64; off <<= 1) {
        #pragma unroll
        for (int i = 0; i < 8; ++i) acc[i] += __shfl_xor(acc[i], off);
    }
    if (slot == 0) {
        float4* dst = (float4*)(x_all + ((size_t)c * MAXL + L) * HID + u * 8);
        dst[0] = make_float4(fmaxf(acc[0], 0.f), fmaxf(acc[1], 0.f),
                             fmaxf(acc[2], 0.f), fmaxf(acc[3], 0.f));
        dst[1] = make_float4(fmaxf(acc[4], 0.f), fmaxf(acc[5], 0.f),
                             fmaxf(acc[6], 0.f), fmaxf(acc[7], 0.f));
    }
}

// ---------- final: logits = x_all[:,3] @ W2 + b2; log_softmax over 32 classes ----------
__global__ void final_kernel(const float* __restrict__ x_all, const float* __restrict__ w2,
                             const float* __restrict__ b2, float* __restrict__ out, int n) {
    int t = blockIdx.x * blockDim.x + threadIdx.x;
    int node = t >> 5;
    int o = t & 31;
    if (node >= n) return;
    const float* xr = x_all + (size_t)node * (MAXL * HID) + 3 * HID;
    float logit = b2[o];
    #pragma unroll
    for (int d = 0; d < HID; ++d) logit = fmaf(xr[d], w2[d * N_CLASS + o], logit);
    float m = logit;
    for (int off = 16; off; off >>= 1) m = fmaxf(m, __shfl_xor(m, off, 32));
    float e = expf(logit - m);
    float sum = e;
    for (int off = 16; off; off >>= 1) sum += __shfl_xor(sum, off, 32);
    out[(size_t)node * N_CLASS + o] = (logit - m) - logf(sum);
}

extern "C" void kernel_launch(void* const* d_in, const int* in_sizes, int n_in,
                              void* d_out, int out_size, void* d_ws, size_t ws_size,
                              hipStream_t stream) {
    const float* x      = (const float*)d_in[0];
    const int*   eidx   = (const int*)d_in[1];     // (2, E)
    const float* lin1_w = (const float*)d_in[2];
    const float* lin1_b = (const float*)d_in[3];
    const float* wq     = (const float*)d_in[4];   // (3, 8, 8, 8)
    const float* bq     = (const float*)d_in[5];   // (3, 64)
    const float* wk     = (const float*)d_in[6];
    const float* bk     = (const float*)d_in[7];
    const float* wv     = (const float*)d_in[8];
    const float* bv     = (const float*)d_in[9];
    const float* lin2_w = (const float*)d_in[10];  // (64, 32)
    const float* lin2_b = (const float*)d_in[11];
    float* out = (float*)d_out;

    const int n  = NN;
    const int E  = NE;
    const int* row = eidx;
    const int* col = eidx + E;

    // workspace layout (16B-aligned where vector-accessed)
    char* ws = (char*)d_ws;
    float*  x_all  = (float*)ws;   ws += (size_t)NN * MAXL * HID * 4;        // 25.6 MB
    f16x2*  Q2     = (f16x2*)ws;   ws += (size_t)NN * 32 * 4;                // 3.2 MB
    f16x2*  KV     = (f16x2*)ws;   ws += (size_t)NN * KVS * 2 * 32 * 4;      // 19.2 MB
    float*  dis    = (float*)ws;   ws += (size_t)NN * 4;
    int*    deg    = (int*)ws;     ws += (size_t)NN * 4;
    int*    rowptr = (int*)ws;     ws += (size_t)NN * 4;
    int*    cursor = (int*)ws;     ws += (size_t)NN * 4;
    int*    csr    = (int*)ws;     ws += (size_t)NE * 4;                     // 1.6 MB
    f16*    wt16   = (f16*)ws;     ws += (size_t)HID * F_IN * 2;             // 32 KB

    // 1. degree + norm + CSR build (+ W1 fp16 transpose)
    hipMemsetAsync(deg, 0, (size_t)NN * 4, stream);
    deg_kernel<<<(E + 255) / 256, 256, 0, stream>>>(col, deg, E);
    dis_kernel<<<(n + 255) / 256, 256, 0, stream>>>(deg, dis, n);
    scan_kernel<<<1, 1024, 0, stream>>>(deg, rowptr, cursor, n);
    scatter_kernel<<<(E + 255) / 256, 256, 0, stream>>>(row, col, cursor, csr, E);
    wprep_kernel<<<(HID * F_IN + 255) / 256, 256, 0, stream>>>(lin1_w, wt16);

    // 2. lin1 (MFMA) -> x_all layer 0
    lin1_mfma_kernel<<<(n + 63) / 64, 256, 0, stream>>>(x, (const f16x8*)wt16, lin1_b, x_all, n);

    // 3. three DNA conv layers
    for (int l = 0; l < 3; ++l) {
        int L = l + 1;
        transform_kernel<<<(n * 32 + 255) / 256, 256, 0, stream>>>(
            x_all, wq + l * 512, bq + l * 64, wk + l * 512, bk + l * 64,
            wv + l * 512, bv + l * 64, Q2, KV, n, L);
        int blocks = (n + 3) / 4;   // 4 nodes (waves) per 256-thread block
        if (L == 1)      gather_kernel<1><<<blocks, 256, 0, stream>>>(rowptr, deg, csr, dis, (const f16x8*)Q2, (const f16x8*)KV, x_all, n);
        else if (L == 2) gather_kernel<2><<<blocks, 256, 0, stream>>>(rowptr, deg, csr, dis, (const f16x8*)Q2, (const f16x8*)KV, x_all, n);
        else             gather_kernel<3><<<blocks, 256, 0, stream>>>(rowptr, deg, csr, dis, (const f16x8*)Q2, (const f16x8*)KV, x_all, n);
    }

    // 4. classifier + log_softmax
    final_kernel<<<(n * N_CLASS + 255) / 256, 256, 0, stream>>>(x_all, lin2_w, lin2_b, out, n);
}

// Round 6
// 304.518 us; speedup vs baseline: 1.8219x; 1.1299x over previous
//
#include <hip/hip_runtime.h>
#include <hip/hip_fp16.h>
#include <math.h>

#define NN 25000
#define NE 400000
#define HID 64
#define F_IN 256
#define N_CLASS 32
#define MAXL 4          // x_all stores up to 4 layer slices
#define KVS 3           // K/V layer slots
#define WPAD 264        // f16 row stride of W^T in LDS (256 + 8 pad -> 4-bank rotate)
#define SCAN_NB 98      // ceil(NN/256)

typedef _Float16 f16;
typedef _Float16 f16x2 __attribute__((ext_vector_type(2)));
typedef _Float16 f16x8 __attribute__((ext_vector_type(8)));
typedef float f32x4 __attribute__((ext_vector_type(4)));

union F16x8 {
    f16x8 v;
    f16x2 h[4];
    __half2 hh[4];
};

__device__ __forceinline__ float dot2(f16x2 a, f16x2 b, float c) {
#if __has_builtin(__builtin_amdgcn_fdot2)
    return __builtin_amdgcn_fdot2(a, b, c, false);
#else
    return c + (float)a[0] * (float)b[0] + (float)a[1] * (float)b[1];
#endif
}

// ---------- degree ----------
__global__ void deg_kernel(const int* __restrict__ col, int* __restrict__ deg, int E) {
    int e = blockIdx.x * blockDim.x + threadIdx.x;
    if (e < E) atomicAdd(&deg[col[e]], 1);
}

// ---------- device-wide exclusive scan, 3 phases ----------
// A: per-block (256 elems) sums
__global__ void scanA_kernel(const int* __restrict__ deg, int* __restrict__ bsum, int n) {
    int t = threadIdx.x;
    int i = blockIdx.x * 256 + t;
    int v = (i < n) ? deg[i] : 0;
    #pragma unroll
    for (int off = 1; off < 64; off <<= 1) v += __shfl_xor(v, off);
    __shared__ int wsum[4];
    if ((t & 63) == 0) wsum[t >> 6] = v;
    __syncthreads();
    if (t == 0) bsum[blockIdx.x] = wsum[0] + wsum[1] + wsum[2] + wsum[3];
}

// B: exclusive scan of block sums (nb <= 128), one 128-thread block
__global__ void scanB_kernel(int* __restrict__ bsum, int nb) {
    __shared__ int s[128];
    int t = threadIdx.x;
    int v = (t < nb) ? bsum[t] : 0;
    s[t] = v;
    __syncthreads();
    for (int off = 1; off < 128; off <<= 1) {
        int u = (t >= off) ? s[t - off] : 0;
        __syncthreads();
        s[t] += u;
        __syncthreads();
    }
    if (t < nb) bsum[t] = s[t] - v;   // exclusive
}

// C: per-block exclusive scan + block base -> rowptr/cursor; dis folded in
__global__ void scanC_kernel(const int* __restrict__ deg, const int* __restrict__ bsum,
                             int* __restrict__ rowptr, int* __restrict__ cursor,
                             float* __restrict__ dis, int n) {
    int t = threadIdx.x;
    int i = blockIdx.x * 256 + t;
    int lane = t & 63, w = t >> 6;
    int v = (i < n) ? deg[i] : 0;
    int x = v;   // inclusive wave scan
    #pragma unroll
    for (int off = 1; off < 64; off <<= 1) {
        int u = __shfl_up(x, off);
        if (lane >= off) x += u;
    }
    __shared__ int wsum[4];
    if (lane == 63) wsum[w] = x;
    __syncthreads();
    int base = bsum[blockIdx.x];
    for (int ww = 0; ww < w; ++ww) base += wsum[ww];
    if (i < n) {
        int excl = base + x - v;
        rowptr[i] = excl;
        cursor[i] = excl;
        dis[i] = rsqrtf((float)(v + 1));   // +1 self loop
    }
}

// ---------- scatter edges into CSR (grouped by destination col) ----------
__global__ void scatter_kernel(const int* __restrict__ row, const int* __restrict__ col,
                               int* __restrict__ cursor, int* __restrict__ csr_src, int E) {
    int e = blockIdx.x * blockDim.x + threadIdx.x;
    if (e >= E) return;
    int c = col[e];
    int p = atomicAdd(&cursor[c], 1);
    csr_src[p] = row[e];
}

// ---------- W1 -> fp16 transposed: wt[n][k] = (f16) w[k*64+n] ----------
__global__ void wprep_kernel(const float* __restrict__ w, f16* __restrict__ wt) {
    int e = blockIdx.x * blockDim.x + threadIdx.x;  // 16384 elements
    int k = e >> 6, nn = e & 63;
    wt[nn * F_IN + k] = (f16)w[e];
}

// ---------- lin1 via MFMA: h = relu(x @ W1 + b1) -> x_all layer 0 ----------
__global__ void __launch_bounds__(256) lin1_mfma_kernel(
        const float* __restrict__ x, const f16x8* __restrict__ wt,
        const float* __restrict__ b, float* __restrict__ x_all, int n) {
    __shared__ f16 wlds[64 * WPAD];
    int t = threadIdx.x;
    #pragma unroll
    for (int j = 0; j < 8; ++j) {                 // stage all 2048 f16x8 units (32 KB)
        int idx = t + j * 256;                    // f16x8 unit index
        int e = idx * 8;
        int nr = e >> 8, k0 = e & 255;
        *(f16x8*)&wlds[nr * WPAD + k0] = wt[idx];
    }
    __syncthreads();
    int wave = t >> 6, lane = t & 63;
    int m = lane & 15, quad = lane >> 4;
    int rowA = blockIdx.x * 64 + wave * 16 + m;
    int rA = min(rowA, n - 1);                    // clamp; masked at store
    const float* xp = x + (size_t)rA * F_IN + quad * 8;
    f32x4 acc[4] = {};
    for (int kk = 0; kk < F_IN; kk += 32) {
        float4 x0 = *(const float4*)(xp + kk);
        float4 x1 = *(const float4*)(xp + kk + 4);
        f16x8 a;
        a[0] = (f16)x0.x; a[1] = (f16)x0.y; a[2] = (f16)x0.z; a[3] = (f16)x0.w;
        a[4] = (f16)x1.x; a[5] = (f16)x1.y; a[6] = (f16)x1.z; a[7] = (f16)x1.w;
        #pragma unroll
        for (int nt = 0; nt < 4; ++nt) {
            f16x8 bf = *(const f16x8*)&wlds[(nt * 16 + m) * WPAD + kk + quad * 8];
            acc[nt] = __builtin_amdgcn_mfma_f32_16x16x32_f16(a, bf, acc[nt], 0, 0, 0);
        }
    }
    int rowC = blockIdx.x * 64 + wave * 16 + quad * 4;
    #pragma unroll
    for (int nt = 0; nt < 4; ++nt) {
        int col = nt * 16 + m;
        float bias = b[col];
        #pragma unroll
        for (int r = 0; r < 4; ++r) {
            int row = rowC + r;
            if (row < n)
                x_all[(size_t)row * (MAXL * HID) + col] = fmaxf(acc[nt][r] + bias, 0.f);
        }
    }
}

// ---------- per-node q/k/v grouped-linear transform (fp16-packed outputs) ----------
__global__ void transform_kernel(const float* __restrict__ x_all,
                                 const float* __restrict__ wq, const float* __restrict__ bq,
                                 const float* __restrict__ wk, const float* __restrict__ bk,
                                 const float* __restrict__ wv, const float* __restrict__ bv,
                                 f16x2* __restrict__ Q2, f16x2* __restrict__ KV,
                                 int n, int L) {
    int t = blockIdx.x * blockDim.x + threadIdx.x;
    int node = t >> 5, u = t & 31;
    if (node >= n) return;
    int g = u >> 2;               // head/group of both dims
    int o0 = (u & 3) * 2;         // within-group output index of dim 2u
    const float* xrow = x_all + (size_t)node * (MAXL * HID);

    {   // Q from layer L-1
        const float* xg = xrow + (L - 1) * HID + g * 8;
        const float* wg = wq + g * 64;
        float a0 = bq[g * 8 + o0], a1 = bq[g * 8 + o0 + 1];
        #pragma unroll
        for (int i = 0; i < 8; ++i) {
            float xv = xg[i];
            a0 = fmaf(xv, wg[i * 8 + o0], a0);
            a1 = fmaf(xv, wg[i * 8 + o0 + 1], a1);
        }
        f16x2 q; q[0] = (f16)a0; q[1] = (f16)a1;
        Q2[(size_t)node * 32 + u] = q;
    }
    for (int ll = 0; ll < L; ++ll) {
        const float* xg = xrow + ll * HID + g * 8;
        const float* wgk = wk + g * 64;
        const float* wgv = wv + g * 64;
        float k0 = bk[g * 8 + o0], k1 = bk[g * 8 + o0 + 1];
        float v0 = bv[g * 8 + o0], v1 = bv[g * 8 + o0 + 1];
        #pragma unroll
        for (int i = 0; i < 8; ++i) {
            float xv = xg[i];
            k0 = fmaf(xv, wgk[i * 8 + o0], k0);
            k1 = fmaf(xv, wgk[i * 8 + o0 + 1], k1);
            v0 = fmaf(xv, wgv[i * 8 + o0], v0);
            v1 = fmaf(xv, wgv[i * 8 + o0 + 1], v1);
        }
        f16x2 kh; kh[0] = (f16)k0; kh[1] = (f16)k1;
        f16x2 vh; vh[0] = (f16)v0; vh[1] = (f16)v1;
        size_t base = ((size_t)node * KVS + ll) * 2;
        KV[(base + 0) * 32 + u] = kh;
        KV[(base + 1) * 32 + u] = vh;
    }
}

// ---------- gather + attend: one wave64 per destination, 8 edges per wave ----------
template <int L>
__global__ void gather_kernel(const int* __restrict__ rowptr, const int* __restrict__ deg,
                              const int* __restrict__ csr_src, const float* __restrict__ dis,
                              const f16x8* __restrict__ Q8, const f16x8* __restrict__ KV8,
                              float* __restrict__ x_all, int n) {
    int wave = (int)((blockIdx.x * (size_t)blockDim.x + threadIdx.x) >> 6);
    int lane = threadIdx.x & 63;
    if (wave >= n) return;
    int c = wave;
    int u = lane & 7;         // head
    int slot = lane >> 3;     // edge slot
    F16x8 q; q.v = Q8[(size_t)c * 8 + u];
    float nc = dis[c];
    int beg = rowptr[c];
    int dc = deg[c] + 1;      // + self loop
    float acc[8];
    #pragma unroll
    for (int i = 0; i < 8; ++i) acc[i] = 0.f;

    for (int j = 0; j < dc; j += 8) {
        int jj = j + slot;
        bool valid = jj < dc;
        int r = c;
        if (valid && jj > 0) r = csr_src[beg + jj - 1];
        float nrm = valid ? nc * dis[r] : 0.f;

        F16x8 kk[L], vv[L];
        size_t rb = (size_t)r * (KVS * 2 * 8);   // f16x8 units per node = 48
        #pragma unroll
        for (int ll = 0; ll < L; ++ll) {
            kk[ll].v = KV8[rb + ll * 16 + u];
            vv[ll].v = KV8[rb + ll * 16 + 8 + u];
        }
        float s[L];
        #pragma unroll
        for (int ll = 0; ll < L; ++ll) {
            float p = 0.f;
            #pragma unroll
            for (int i2 = 0; i2 < 4; ++i2) p = dot2(q.h[i2], kk[ll].h[i2], p);
            s[ll] = p * 0.35355339059327373f;   // 1/sqrt(8)
        }
        float m = s[0];
        #pragma unroll
        for (int ll = 1; ll < L; ++ll) m = fmaxf(m, s[ll]);
        float sum = 0.f;
        #pragma unroll
        for (int ll = 0; ll < L; ++ll) { s[ll] = __expf(s[ll] - m); sum += s[ll]; }
        float inv = nrm / sum;                   // fold norm into probs

        __half2 ha[4];
        #pragma unroll
        for (int i2 = 0; i2 < 4; ++i2) ha[i2] = __float2half2_rn(0.f);
        #pragma unroll
        for (int ll = 0; ll < L; ++ll) {
            __half2 p2 = __float2half2_rn(s[ll] * inv);
            #pragma unroll
            for (int i2 = 0; i2 < 4; ++i2) ha[i2] = __hfma2(p2, vv[ll].hh[i2], ha[i2]);
        }
        #pragma unroll
        for (int i2 = 0; i2 < 4; ++i2) {
            float2 f = __half22float2(ha[i2]);
            acc[i2 * 2]     += f.x;
            acc[i2 * 2 + 1] += f.y;
        }
    }
    // reduce the 8 edge slots (once per node)
    #pragma unroll
    for (int off = 8; off < 64; off <<= 1) {
        #pragma unroll
        for (int i = 0; i < 8; ++i) acc[i] += __shfl_xor(acc[i], off);
    }
    if (slot == 0) {
        float4* dst = (float4*)(x_all + ((size_t)c * MAXL + L) * HID + u * 8);
        dst[0] = make_float4(fmaxf(acc[0], 0.f), fmaxf(acc[1], 0.f),
                             fmaxf(acc[2], 0.f), fmaxf(acc[3], 0.f));
        dst[1] = make_float4(fmaxf(acc[4], 0.f), fmaxf(acc[5], 0.f),
                             fmaxf(acc[6], 0.f), fmaxf(acc[7], 0.f));
    }
}

// ---------- final: logits = x_all[:,3] @ W2 + b2; log_softmax over 32 classes ----------
__global__ void final_kernel(const float* __restrict__ x_all, const float* __restrict__ w2,
                             const float* __restrict__ b2, float* __restrict__ out, int n) {
    int t = blockIdx.x * blockDim.x + threadIdx.x;
    int node = t >> 5;
    int o = t & 31;
    if (node >= n) return;
    const float* xr = x_all + (size_t)node * (MAXL * HID) + 3 * HID;
    float logit = b2[o];
    #pragma unroll
    for (int d = 0; d < HID; ++d) logit = fmaf(xr[d], w2[d * N_CLASS + o], logit);
    float m = logit;
    for (int off = 16; off; off >>= 1) m = fmaxf(m, __shfl_xor(m, off, 32));
    float e = expf(logit - m);
    float sum = e;
    for (int off = 16; off; off >>= 1) sum += __shfl_xor(sum, off, 32);
    out[(size_t)node * N_CLASS + o] = (logit - m) - logf(sum);
}

extern "C" void kernel_launch(void* const* d_in, const int* in_sizes, int n_in,
                              void* d_out, int out_size, void* d_ws, size_t ws_size,
                              hipStream_t stream) {
    const float* x      = (const float*)d_in[0];
    const int*   eidx   = (const int*)d_in[1];     // (2, E)
    const float* lin1_w = (const float*)d_in[2];
    const float* lin1_b = (const float*)d_in[3];
    const float* wq     = (const float*)d_in[4];   // (3, 8, 8, 8)
    const float* bq     = (const float*)d_in[5];   // (3, 64)
    const float* wk     = (const float*)d_in[6];
    const float* bk     = (const float*)d_in[7];
    const float* wv     = (const float*)d_in[8];
    const float* bv     = (const float*)d_in[9];
    const float* lin2_w = (const float*)d_in[10];  // (64, 32)
    const float* lin2_b = (const float*)d_in[11];
    float* out = (float*)d_out;

    const int n  = NN;
    const int E  = NE;
    const int* row = eidx;
    const int* col = eidx + E;

    // workspace layout (16B-aligned where vector-accessed)
    char* ws = (char*)d_ws;
    float*  x_all  = (float*)ws;   ws += (size_t)NN * MAXL * HID * 4;        // 25.6 MB
    f16x2*  Q2     = (f16x2*)ws;   ws += (size_t)NN * 32 * 4;                // 3.2 MB
    f16x2*  KV     = (f16x2*)ws;   ws += (size_t)NN * KVS * 2 * 32 * 4;      // 19.2 MB
    float*  dis    = (float*)ws;   ws += (size_t)NN * 4;
    int*    deg    = (int*)ws;     ws += (size_t)NN * 4;
    int*    rowptr = (int*)ws;     ws += (size_t)NN * 4;
    int*    cursor = (int*)ws;     ws += (size_t)NN * 4;
    int*    csr    = (int*)ws;     ws += (size_t)NE * 4;                     // 1.6 MB
    f16*    wt16   = (f16*)ws;     ws += (size_t)HID * F_IN * 2;             // 32 KB
    int*    bsum   = (int*)ws;     ws += 128 * 4;

    // 1. degree + norm + CSR build (+ W1 fp16 transpose)
    hipMemsetAsync(deg, 0, (size_t)NN * 4, stream);
    deg_kernel<<<(E + 255) / 256, 256, 0, stream>>>(col, deg, E);
    scanA_kernel<<<SCAN_NB, 256, 0, stream>>>(deg, bsum, n);
    scanB_kernel<<<1, 128, 0, stream>>>(bsum, SCAN_NB);
    scanC_kernel<<<SCAN_NB, 256, 0, stream>>>(deg, bsum, rowptr, cursor, dis, n);
    scatter_kernel<<<(E + 255) / 256, 256, 0, stream>>>(row, col, cursor, csr, E);
    wprep_kernel<<<(HID * F_IN + 255) / 256, 256, 0, stream>>>(lin1_w, wt16);

    // 2. lin1 (MFMA) -> x_all layer 0
    lin1_mfma_kernel<<<(n + 63) / 64, 256, 0, stream>>>(x, (const f16x8*)wt16, lin1_b, x_all, n);

    // 3. three DNA conv layers
    for (int l = 0; l < 3; ++l) {
        int L = l + 1;
        transform_kernel<<<(n * 32 + 255) / 256, 256, 0, stream>>>(
            x_all, wq + l * 512, bq + l * 64, wk + l * 512, bk + l * 64,
            wv + l * 512, bv + l * 64, Q2, KV, n, L);
        int blocks = (n + 3) / 4;   // 4 nodes (waves) per 256-thread block
        if (L == 1)      gather_kernel<1><<<blocks, 256, 0, stream>>>(rowptr, deg, csr, dis, (const f16x8*)Q2, (const f16x8*)KV, x_all, n);
        else if (L == 2) gather_kernel<2><<<blocks, 256, 0, stream>>>(rowptr, deg, csr, dis, (const f16x8*)Q2, (const f16x8*)KV, x_all, n);
        else             gather_kernel<3><<<blocks, 256, 0, stream>>>(rowptr, deg, csr, dis, (const f16x8*)Q2, (const f16x8*)KV, x_all, n);
    }

    // 4. classifier + log_softmax
    final_kernel<<<(n * N_CLASS + 255) / 256, 256, 0, stream>>>(x_all, lin2_w, lin2_b, out, n);
}